// Round 1
// baseline (464.913 us; speedup 1.0000x reference)
//
#include <hip/hip_runtime.h>
#include <hip/hip_bf16.h>
#include <hip/hip_fp16.h>

typedef float f32x4 __attribute__((ext_vector_type(4)));
typedef _Float16 half8 __attribute__((ext_vector_type(8)));
typedef unsigned short u16;

#define DEVI __device__ __forceinline__

DEVI void async_cp16(void* lds, const void* g) {
  __builtin_amdgcn_global_load_lds(
      (const __attribute__((address_space(1))) void*)g,
      (__attribute__((address_space(3))) void*)lds,
      16, 0, 0);
}

DEVI u16 f2h(float x) {
  union { _Float16 h; u16 u; } v;
  v.h = (_Float16)x;
  return v.u;
}

// ---------------- convert x fp32 -> fp16 ----------------
__global__ __launch_bounds__(256) void k_convert_x(const float* __restrict__ in,
                                                   u16* __restrict__ out) {
  int idx = (blockIdx.x * 256 + threadIdx.x) * 4;
  float4 v = *(const float4*)(in + idx);
  ushort4 o;
  o.x = f2h(v.x); o.y = f2h(v.y); o.z = f2h(v.z); o.w = f2h(v.w);
  *(ushort4*)(out + idx) = o;
}

// ---------------- transpose + convert: out[c+rowoff][r] = in[r][c] ----------------
__global__ __launch_bounds__(256) void k_transpose(const float* __restrict__ in, int ldin,
                                                   u16* __restrict__ out, int ldout,
                                                   int rowoff) {
  __shared__ u16 tile[64][65];
  int r0 = blockIdx.y * 64, c0 = blockIdx.x * 64;
  int tx = threadIdx.x & 63, ty = threadIdx.x >> 6;
  for (int rr = ty; rr < 64; rr += 4)
    tile[rr][tx] = f2h(in[(size_t)(r0 + rr) * ldin + (c0 + tx)]);
  __syncthreads();
  for (int rr = ty; rr < 64; rr += 4)
    out[(size_t)(c0 + rr + rowoff) * ldout + (r0 + tx)] = tile[tx][rr];
}

// ---------------- generic GEMM: C[M][N] fp32 = A[M][K]f16 @ B[N][K]f16^T ----------------
// grid (N/128, M/128), block 256. 128x128 tile, BK=32, m97-style global_load_lds staging.
__global__ __launch_bounds__(256)
void k_gemm(const u16* __restrict__ A, int lda,
            const u16* __restrict__ B, int ldb,
            float* __restrict__ C, int ldc, int K) {
  __shared__ __align__(16) u16 As[128 * 32];
  __shared__ __align__(16) u16 Bs[128 * 32];
  const int i0 = blockIdx.y * 128, j0 = blockIdx.x * 128;
  const int tid = threadIdx.x;
  const int wave = tid >> 6, lane = tid & 63;
  const int wm = (wave >> 1) * 64, wn = (wave & 1) * 64;
  const int quad = lane >> 4, r = lane & 15;

  f32x4 acc[4][4] = {};

  const int ar = tid >> 2, ac = (tid & 3) * 8;   // 16B chunk: row=tid/4, col=(tid%4)*8
  const u16* ag0 = A + (size_t)(i0 + ar) * lda + ac;
  const u16* ag1 = ag0 + (size_t)64 * lda;
  const u16* bg0 = B + (size_t)(j0 + ar) * ldb + ac;
  const u16* bg1 = bg0 + (size_t)64 * ldb;
  u16* al0 = As + tid * 8;
  u16* al1 = As + (tid + 256) * 8;
  u16* bl0 = Bs + tid * 8;
  u16* bl1 = Bs + (tid + 256) * 8;

  for (int k0 = 0; k0 < K; k0 += 32) {
    async_cp16(al0, ag0); async_cp16(al1, ag1);
    async_cp16(bl0, bg0); async_cp16(bl1, bg1);
    ag0 += 32; ag1 += 32; bg0 += 32; bg1 += 32;
    __syncthreads();
    half8 af[4], bf[4];
#pragma unroll
    for (int t = 0; t < 4; t++) af[t] = *(const half8*)(As + (wm + t * 16 + r) * 32 + quad * 8);
#pragma unroll
    for (int t = 0; t < 4; t++) bf[t] = *(const half8*)(Bs + (wn + t * 16 + r) * 32 + quad * 8);
#pragma unroll
    for (int ta = 0; ta < 4; ta++)
#pragma unroll
      for (int tb = 0; tb < 4; tb++)
        acc[ta][tb] = __builtin_amdgcn_mfma_f32_16x16x32_f16(af[ta], bf[tb], acc[ta][tb], 0, 0, 0);
    __syncthreads();
  }
#pragma unroll
  for (int ta = 0; ta < 4; ta++) {
    int row = i0 + wm + ta * 16 + quad * 4;
#pragma unroll
    for (int tb = 0; tb < 4; tb++) {
      int col = j0 + wn + tb * 16 + r;
      float* cp = C + (size_t)row * ldc + col;
#pragma unroll
      for (int v = 0; v < 4; v++) cp[(size_t)v * ldc] = acc[ta][tb][v];
    }
  }
}

// ---------------- RoPE: qkv fp32 -> q,k fp16 (rotated) ----------------
__global__ __launch_bounds__(256)
void k_rope(const float* __restrict__ qkv, const int* __restrict__ pos,
            u16* __restrict__ qh, u16* __restrict__ kh) {
  int idx = blockIdx.x * 256 + threadIdx.x;
  const int TOTAL_Q = 2048 * 1024;  // s * (8 heads * 128 pairs)
  int s, i;
  const float* src;
  u16* dst;
  if (idx < TOTAL_Q) {
    s = idx >> 10;
    int hi = idx & 1023;
    int hd = hi >> 7;
    i = hi & 127;
    src = qkv + (size_t)s * 2560 + hd * 256;
    dst = qh + (size_t)s * 2048 + hd * 256;
  } else {
    int t = idx - TOTAL_Q;  // 0 .. 2048*128-1
    s = t >> 7;
    i = t & 127;
    src = qkv + (size_t)s * 2560 + 2048;
    dst = kh + (size_t)s * 256;
  }
  float p = (float)pos[s];
  // inv_freq = 10000^(-i/128) = exp(-i * ln(1e4)/128)
  float freq = __expf((float)i * (-9.210340371976184f / 128.0f)) * p;
  float sn, cs;
  sincosf(freq, &sn, &cs);
  float a = src[i], b = src[i + 128];
  dst[i]       = f2h(a * cs - b * sn);
  dst[i + 128] = f2h(b * cs + a * sn);
}

// ---------------- scores: attn[h][i][j] = scale * q_h[i]·k[j], causal ----------------
__global__ __launch_bounds__(256)
void k_scores(const u16* __restrict__ qh, const u16* __restrict__ kh,
              float* __restrict__ attn) {
  const int i0 = blockIdx.y * 128, j0 = blockIdx.x * 128;
  if (j0 > i0) return;  // fully masked tile (attn pre-zeroed)
  const int h = blockIdx.z;
  const u16* A = qh + h * 256;        // lda 2048, K=256
  __shared__ __align__(16) u16 As[128 * 32];
  __shared__ __align__(16) u16 Bs[128 * 32];
  const int tid = threadIdx.x;
  const int wave = tid >> 6, lane = tid & 63;
  const int wm = (wave >> 1) * 64, wn = (wave & 1) * 64;
  const int quad = lane >> 4, r = lane & 15;

  f32x4 acc[4][4] = {};

  const int ar = tid >> 2, ac = (tid & 3) * 8;
  const u16* ag0 = A + (size_t)(i0 + ar) * 2048 + ac;
  const u16* ag1 = ag0 + (size_t)64 * 2048;
  const u16* bg0 = kh + (size_t)(j0 + ar) * 256 + ac;
  const u16* bg1 = bg0 + (size_t)64 * 256;
  u16* al0 = As + tid * 8;
  u16* al1 = As + (tid + 256) * 8;
  u16* bl0 = Bs + tid * 8;
  u16* bl1 = Bs + (tid + 256) * 8;

  for (int k0 = 0; k0 < 256; k0 += 32) {
    async_cp16(al0, ag0); async_cp16(al1, ag1);
    async_cp16(bl0, bg0); async_cp16(bl1, bg1);
    ag0 += 32; ag1 += 32; bg0 += 32; bg1 += 32;
    __syncthreads();
    half8 af[4], bf[4];
#pragma unroll
    for (int t = 0; t < 4; t++) af[t] = *(const half8*)(As + (wm + t * 16 + r) * 32 + quad * 8);
#pragma unroll
    for (int t = 0; t < 4; t++) bf[t] = *(const half8*)(Bs + (wn + t * 16 + r) * 32 + quad * 8);
#pragma unroll
    for (int ta = 0; ta < 4; ta++)
#pragma unroll
      for (int tb = 0; tb < 4; tb++)
        acc[ta][tb] = __builtin_amdgcn_mfma_f32_16x16x32_f16(af[ta], bf[tb], acc[ta][tb], 0, 0, 0);
    __syncthreads();
  }
  float* out = attn + ((size_t)h << 22);
#pragma unroll
  for (int ta = 0; ta < 4; ta++) {
#pragma unroll
    for (int tb = 0; tb < 4; tb++) {
      int col = j0 + wn + tb * 16 + r;
#pragma unroll
      for (int v = 0; v < 4; v++) {
        int row = i0 + wm + ta * 16 + quad * 4 + v;
        if (col <= row)
          out[(size_t)row * 2048 + col] = acc[ta][tb][v] * 0.0625f;
      }
    }
  }
}

// ---------------- row softmax over j<=i, in place ----------------
__global__ __launch_bounds__(256)
void k_softmax(float* __restrict__ attn) {
  int blk = blockIdx.x;           // h*2048 + i
  int h = blk >> 11, i = blk & 2047;
  float* p = attn + ((size_t)h << 22) + (size_t)i * 2048;
  int len = i + 1;
  int tid = threadIdx.x;
  float vals[8];
  int nv = 0;
  float m = -1e30f;
  for (int j = tid; j < len; j += 256) {
    float x = p[j];
    vals[nv++] = x;
    m = fmaxf(m, x);
  }
#pragma unroll
  for (int off = 32; off; off >>= 1) m = fmaxf(m, __shfl_down(m, off));
  __shared__ float wred[4];
  if ((tid & 63) == 0) wred[tid >> 6] = m;
  __syncthreads();
  m = fmaxf(fmaxf(wred[0], wred[1]), fmaxf(wred[2], wred[3]));
  float s = 0.f;
  for (int t = 0; t < nv; t++) {
    vals[t] = __expf(vals[t] - m);
    s += vals[t];
  }
#pragma unroll
  for (int off = 32; off; off >>= 1) s += __shfl_down(s, off);
  __shared__ float wsum[4];
  if ((tid & 63) == 0) wsum[tid >> 6] = s;
  __syncthreads();
  s = wsum[0] + wsum[1] + wsum[2] + wsum[3];
  float inv = 1.0f / s;
  nv = 0;
  for (int j = tid; j < len; j += 256) p[j] = vals[nv++] * inv;
}

// ---------------- PV: o[i][h*256+d] = sum_j attn[h][i][j] * v[j][d] ----------------
// A = attn fp32 (converted to fp16 during LDS staging), B = vT f16 [256][2048]
__global__ __launch_bounds__(256)
void k_pv(const float* __restrict__ attn, const u16* __restrict__ vT,
          u16* __restrict__ o) {
  const int h = blockIdx.z;
  const int i0 = blockIdx.y * 128;
  const int n0 = blockIdx.x * 128;
  const float* Ab = attn + ((size_t)h << 22);
  const int kmax = i0 + 128;      // causal: j-tiles through the diagonal only
  __shared__ __align__(16) u16 As[128 * 32];
  __shared__ __align__(16) u16 Bs[128 * 32];
  const int tid = threadIdx.x;
  const int wave = tid >> 6, lane = tid & 63;
  const int wm = (wave >> 1) * 64, wn = (wave & 1) * 64;
  const int quad = lane >> 4, r = lane & 15;

  f32x4 acc[4][4] = {};

  const int br = tid >> 2, bc = (tid & 3) * 8;
  const u16* bg0 = vT + (size_t)(n0 + br) * 2048 + bc;
  const u16* bg1 = bg0 + (size_t)64 * 2048;
  u16* bl0 = Bs + tid * 8;
  u16* bl1 = Bs + (tid + 256) * 8;
  const int arr = tid >> 3, acc4 = (tid & 7) * 4;  // float4 chunk: row=tid/8, col=(tid%8)*4
  const float* ag = Ab + (size_t)(i0 + arr) * 2048 + acc4;

  for (int k0 = 0; k0 < kmax; k0 += 32) {
    async_cp16(bl0, bg0); async_cp16(bl1, bg1);
    bg0 += 32; bg1 += 32;
#pragma unroll
    for (int it = 0; it < 4; it++) {
      float4 v = *(const float4*)(ag + (size_t)(it * 32) * 2048 + k0);
      ushort4 w;
      w.x = f2h(v.x); w.y = f2h(v.y); w.z = f2h(v.z); w.w = f2h(v.w);
      *(ushort4*)(As + (arr + it * 32) * 32 + acc4) = w;
    }
    __syncthreads();
    half8 af[4], bf[4];
#pragma unroll
    for (int t = 0; t < 4; t++) af[t] = *(const half8*)(As + (wm + t * 16 + r) * 32 + quad * 8);
#pragma unroll
    for (int t = 0; t < 4; t++) bf[t] = *(const half8*)(Bs + (wn + t * 16 + r) * 32 + quad * 8);
#pragma unroll
    for (int ta = 0; ta < 4; ta++)
#pragma unroll
      for (int tb = 0; tb < 4; tb++)
        acc[ta][tb] = __builtin_amdgcn_mfma_f32_16x16x32_f16(af[ta], bf[tb], acc[ta][tb], 0, 0, 0);
    __syncthreads();
  }
#pragma unroll
  for (int ta = 0; ta < 4; ta++) {
    int row = i0 + wm + ta * 16 + quad * 4;
#pragma unroll
    for (int tb = 0; tb < 4; tb++) {
      int col = h * 256 + n0 + wn + tb * 16 + r;
#pragma unroll
      for (int v = 0; v < 4; v++)
        o[(size_t)(row + v) * 2048 + col] = f2h(acc[ta][tb][v]);
    }
  }
}

extern "C" void kernel_launch(void* const* d_in, const int* in_sizes, int n_in,
                              void* d_out, int out_size, void* d_ws, size_t ws_size,
                              hipStream_t stream) {
  const float* x   = (const float*)d_in[0];
  const int*   pos = (const int*)d_in[1];
  // d_in[2] attention_mask: exactly causal 0/-1e9 — handled structurally
  const float* w_q = (const float*)d_in[3];
  const float* w_k = (const float*)d_in[4];
  const float* w_v = (const float*)d_in[5];
  const float* w_o = (const float*)d_in[6];

  float* out  = (float*)d_out;                        // [2048][2048]
  float* attn = out + (size_t)2048 * 2048;            // [8][2048][2048]

  char* ws = (char*)d_ws;
  float* qkv   = (float*)ws;                                   // 2048*2560 fp32
  u16*   xb    = (u16*)(ws + (size_t)2048 * 2560 * 4);         // 2048*2048
  u16*   wqkvT = xb + (size_t)2048 * 2048;                     // 2560*2048
  u16*   woT   = wqkvT + (size_t)2560 * 2048;                  // 2048*2048
  u16*   qh    = woT + (size_t)2048 * 2048;                    // 2048*2048
  u16*   kh    = qh + (size_t)2048 * 2048;                     // 2048*256
  u16*   vT    = kh + (size_t)2048 * 256;                      // 256*2048
  u16*   ob    = vT + (size_t)256 * 2048;                      // 2048*2048

  // zero attn (upper triangle stays exactly 0, matching exp(-1e9) underflow)
  hipMemsetAsync(attn, 0, (size_t)8 * 2048 * 2048 * sizeof(float), stream);

  k_convert_x<<<4096, 256, 0, stream>>>(x, xb);
  k_transpose<<<dim3(32, 32), 256, 0, stream>>>(w_q, 2048, wqkvT, 2048, 0);
  k_transpose<<<dim3(4, 32), 256, 0, stream>>>(w_k, 256, wqkvT, 2048, 2048);
  k_transpose<<<dim3(4, 32), 256, 0, stream>>>(w_v, 256, wqkvT, 2048, 2304);
  k_transpose<<<dim3(32, 32), 256, 0, stream>>>(w_o, 2048, woT, 2048, 0);

  // qkv = x @ [w_q|w_k|w_v]  (M=2048, N=2560, K=2048)
  k_gemm<<<dim3(20, 16), 256, 0, stream>>>(xb, 2048, wqkvT, 2048, qkv, 2560, 2048);

  // rope -> qh, kh (fp16); v^T via transpose of qkv cols 2304..2559
  k_rope<<<(2048 * 1024 + 2048 * 128) / 256, 256, 0, stream>>>(qkv, pos, qh, kh);
  k_transpose<<<dim3(4, 32), 256, 0, stream>>>(qkv + 2304, 2560, vT, 2048, 0);

  k_scores<<<dim3(16, 16, 8), 256, 0, stream>>>(qh, kh, attn);
  k_softmax<<<8 * 2048, 256, 0, stream>>>(attn);
  k_pv<<<dim3(2, 16, 8), 256, 0, stream>>>(attn, vT, ob);

  // out = o @ w_o  (M=2048, N=2048, K=2048)
  k_gemm<<<dim3(16, 16), 256, 0, stream>>>(ob, 2048, woT, 2048, out, 2048, 2048);
}

// Round 2
// 435.030 us; speedup vs baseline: 1.0687x; 1.0687x over previous
//
#include <hip/hip_runtime.h>
#include <hip/hip_bf16.h>
#include <hip/hip_fp16.h>

typedef float f32x4 __attribute__((ext_vector_type(4)));
typedef _Float16 half8 __attribute__((ext_vector_type(8)));
typedef unsigned short u16;

#define DEVI __device__ __forceinline__

DEVI void async_cp16(void* lds, const void* g) {
  __builtin_amdgcn_global_load_lds(
      (const __attribute__((address_space(1))) void*)g,
      (__attribute__((address_space(3))) void*)lds,
      16, 0, 0);
}

DEVI u16 f2h(float x) {
  union { _Float16 h; u16 u; } v;
  v.h = (_Float16)x;
  return v.u;
}

// one 16x16x32 wave-tile compute step from staged LDS buffers
DEVI void gemm_step(const u16* __restrict__ As, const u16* __restrict__ Bs,
                    int wm, int wn, int quad, int r, f32x4 (&acc)[4][4]) {
  half8 af[4], bf[4];
#pragma unroll
  for (int t = 0; t < 4; t++) af[t] = *(const half8*)(As + (wm + t * 16 + r) * 32 + quad * 8);
#pragma unroll
  for (int t = 0; t < 4; t++) bf[t] = *(const half8*)(Bs + (wn + t * 16 + r) * 32 + quad * 8);
#pragma unroll
  for (int ta = 0; ta < 4; ta++)
#pragma unroll
    for (int tb = 0; tb < 4; tb++)
      acc[ta][tb] = __builtin_amdgcn_mfma_f32_16x16x32_f16(af[ta], bf[tb], acc[ta][tb], 0, 0, 0);
}

// ---------------- convert x fp32 -> fp16 ----------------
__global__ __launch_bounds__(256) void k_convert_x(const float* __restrict__ in,
                                                   u16* __restrict__ out) {
  int idx = (blockIdx.x * 256 + threadIdx.x) * 4;
  float4 v = *(const float4*)(in + idx);
  ushort4 o;
  o.x = f2h(v.x); o.y = f2h(v.y); o.z = f2h(v.z); o.w = f2h(v.w);
  *(ushort4*)(out + idx) = o;
}

// ---------------- generic transpose + convert (used for vT) ----------------
__global__ __launch_bounds__(256) void k_transpose(const float* __restrict__ in, int ldin,
                                                   u16* __restrict__ out, int ldout,
                                                   int rowoff) {
  __shared__ u16 tile[64][65];
  int r0 = blockIdx.y * 64, c0 = blockIdx.x * 64;
  int tx = threadIdx.x & 63, ty = threadIdx.x >> 6;
  for (int rr = ty; rr < 64; rr += 4)
    tile[rr][tx] = f2h(in[(size_t)(r0 + rr) * ldin + (c0 + tx)]);
  __syncthreads();
  for (int rr = ty; rr < 64; rr += 4)
    out[(size_t)(c0 + rr + rowoff) * ldout + (r0 + tx)] = tile[tx][rr];
}

// ---------------- all 4 weight transposes in one launch ----------------
// grid (72, 32): x 0..31 -> w_q cols, 32..35 -> w_k, 36..39 -> w_v, 40..71 -> w_o
__global__ __launch_bounds__(256)
void k_transpose_all(const float* __restrict__ wq, const float* __restrict__ wk,
                     const float* __restrict__ wv, const float* __restrict__ wo,
                     u16* __restrict__ wqkvT, u16* __restrict__ woT) {
  __shared__ u16 tile[64][65];
  int bx = blockIdx.x;
  const float* in; int ldin, rowoff, cx; u16* out;
  if (bx < 32)      { in = wq; ldin = 2048; out = wqkvT; rowoff = 0;    cx = bx; }
  else if (bx < 36) { in = wk; ldin = 256;  out = wqkvT; rowoff = 2048; cx = bx - 32; }
  else if (bx < 40) { in = wv; ldin = 256;  out = wqkvT; rowoff = 2304; cx = bx - 36; }
  else              { in = wo; ldin = 2048; out = woT;   rowoff = 0;    cx = bx - 40; }
  int r0 = blockIdx.y * 64, c0 = cx * 64;
  int tx = threadIdx.x & 63, ty = threadIdx.x >> 6;
  for (int rr = ty; rr < 64; rr += 4)
    tile[rr][tx] = f2h(in[(size_t)(r0 + rr) * ldin + (c0 + tx)]);
  __syncthreads();
  for (int rr = ty; rr < 64; rr += 4)
    out[(size_t)(c0 + rr + rowoff) * 2048 + (r0 + tx)] = tile[tx][rr];
}

// ---------------- GEMM: C[M][N] fp32 = A[M][K]f16 @ B[N][K]f16^T ----------------
// 128x128 tile, BK=32, double-buffered LDS (2-stage pipeline): at ~1 block/CU
// there is no TLP to hide staging, so prefetch(k+1) must overlap compute(k).
__global__ __launch_bounds__(256)
void k_gemm(const u16* __restrict__ A, int lda,
            const u16* __restrict__ B, int ldb,
            float* __restrict__ C, int ldc, int K) {
  __shared__ __align__(16) u16 As[2][128 * 32];
  __shared__ __align__(16) u16 Bs[2][128 * 32];
  const int i0 = blockIdx.y * 128, j0 = blockIdx.x * 128;
  const int tid = threadIdx.x;
  const int wave = tid >> 6, lane = tid & 63;
  const int wm = (wave >> 1) * 64, wn = (wave & 1) * 64;
  const int quad = lane >> 4, r = lane & 15;

  f32x4 acc[4][4] = {};

  const int ar = tid >> 2, ac = (tid & 3) * 8;
  const u16* ag0 = A + (size_t)(i0 + ar) * lda + ac;
  const u16* ag1 = ag0 + (size_t)64 * lda;
  const u16* bg0 = B + (size_t)(j0 + ar) * ldb + ac;
  const u16* bg1 = bg0 + (size_t)64 * ldb;
  const int l0 = tid * 8, l1 = (tid + 256) * 8;

  // prologue: tile 0 -> buf 0
  async_cp16(As[0] + l0, ag0); async_cp16(As[0] + l1, ag1);
  async_cp16(Bs[0] + l0, bg0); async_cp16(Bs[0] + l1, bg1);
  ag0 += 32; ag1 += 32; bg0 += 32; bg1 += 32;
  __syncthreads();

  const int nk = K >> 5;  // even for all callers (K=2048)
  for (int kt = 0; kt < nk; kt += 2) {
    if (kt + 1 < nk) {
      async_cp16(As[1] + l0, ag0); async_cp16(As[1] + l1, ag1);
      async_cp16(Bs[1] + l0, bg0); async_cp16(Bs[1] + l1, bg1);
      ag0 += 32; ag1 += 32; bg0 += 32; bg1 += 32;
    }
    gemm_step(As[0], Bs[0], wm, wn, quad, r, acc);
    __syncthreads();
    if (kt + 2 < nk) {
      async_cp16(As[0] + l0, ag0); async_cp16(As[0] + l1, ag1);
      async_cp16(Bs[0] + l0, bg0); async_cp16(Bs[0] + l1, bg1);
      ag0 += 32; ag1 += 32; bg0 += 32; bg1 += 32;
    }
    if (kt + 1 < nk) {
      gemm_step(As[1], Bs[1], wm, wn, quad, r, acc);
      __syncthreads();
    }
  }
#pragma unroll
  for (int ta = 0; ta < 4; ta++) {
    int row = i0 + wm + ta * 16 + quad * 4;
#pragma unroll
    for (int tb = 0; tb < 4; tb++) {
      int col = j0 + wn + tb * 16 + r;
      float* cp = C + (size_t)row * ldc + col;
#pragma unroll
      for (int v = 0; v < 4; v++) cp[(size_t)v * ldc] = acc[ta][tb][v];
    }
  }
}

// ---------------- RoPE: qkv fp32 -> q,k fp16 (rotated) ----------------
__global__ __launch_bounds__(256)
void k_rope(const float* __restrict__ qkv, const int* __restrict__ pos,
            u16* __restrict__ qh, u16* __restrict__ kh) {
  int idx = blockIdx.x * 256 + threadIdx.x;
  const int TOTAL_Q = 2048 * 1024;
  int s, i;
  const float* src;
  u16* dst;
  if (idx < TOTAL_Q) {
    s = idx >> 10;
    int hi = idx & 1023;
    int hd = hi >> 7;
    i = hi & 127;
    src = qkv + (size_t)s * 2560 + hd * 256;
    dst = qh + (size_t)s * 2048 + hd * 256;
  } else {
    int t = idx - TOTAL_Q;
    s = t >> 7;
    i = t & 127;
    src = qkv + (size_t)s * 2560 + 2048;
    dst = kh + (size_t)s * 256;
  }
  float p = (float)pos[s];
  float freq = __expf((float)i * (-9.210340371976184f / 128.0f)) * p;
  float sn, cs;
  sincosf(freq, &sn, &cs);
  float a = src[i], b = src[i + 128];
  dst[i]       = f2h(a * cs - b * sn);
  dst[i + 128] = f2h(b * cs + a * sn);
}

// ---------------- scores: attn[h][i][j] = scale * q_h[i]·k[j], causal ----------------
// Upper tiles (j0>i0) zero-fill their output (replaces the 128MB memset);
// diagonal tiles store (col<=row ? v*scale : 0) branch-free.
__global__ __launch_bounds__(256)
void k_scores(const u16* __restrict__ qh, const u16* __restrict__ kh,
              float* __restrict__ attn) {
  const int i0 = blockIdx.y * 128, j0 = blockIdx.x * 128;
  const int h = blockIdx.z;
  const int tid = threadIdx.x;
  float* outb = attn + ((size_t)h << 22);
  if (j0 > i0) {  // fully-masked tile: write exact zeros (softmax leaves them)
    float4 z = {0.f, 0.f, 0.f, 0.f};
    int row = tid >> 5, col4 = (tid & 31) * 4;
    for (int s = 0; s < 16; s++)
      *(float4*)(outb + (size_t)(i0 + s * 8 + row) * 2048 + j0 + col4) = z;
    return;
  }
  const u16* A = qh + h * 256;
  __shared__ __align__(16) u16 As[128 * 32];
  __shared__ __align__(16) u16 Bs[128 * 32];
  const int wave = tid >> 6, lane = tid & 63;
  const int wm = (wave >> 1) * 64, wn = (wave & 1) * 64;
  const int quad = lane >> 4, r = lane & 15;

  f32x4 acc[4][4] = {};

  const int ar = tid >> 2, ac = (tid & 3) * 8;
  const u16* ag0 = A + (size_t)(i0 + ar) * 2048 + ac;
  const u16* ag1 = ag0 + (size_t)64 * 2048;
  const u16* bg0 = kh + (size_t)(j0 + ar) * 256 + ac;
  const u16* bg1 = bg0 + (size_t)64 * 256;
  const int l0 = tid * 8, l1 = (tid + 256) * 8;

  for (int k0 = 0; k0 < 256; k0 += 32) {
    async_cp16(As + l0, ag0); async_cp16(As + l1, ag1);
    async_cp16(Bs + l0, bg0); async_cp16(Bs + l1, bg1);
    ag0 += 32; ag1 += 32; bg0 += 32; bg1 += 32;
    __syncthreads();
    gemm_step(As, Bs, wm, wn, quad, r, acc);
    __syncthreads();
  }
#pragma unroll
  for (int ta = 0; ta < 4; ta++) {
#pragma unroll
    for (int tb = 0; tb < 4; tb++) {
      int col = j0 + wn + tb * 16 + r;
#pragma unroll
      for (int v = 0; v < 4; v++) {
        int row = i0 + wm + ta * 16 + quad * 4 + v;
        outb[(size_t)row * 2048 + col] = (col <= row) ? acc[ta][tb][v] * 0.0625f : 0.0f;
      }
    }
  }
}

// ---------------- row softmax over j<=i, in place ----------------
__global__ __launch_bounds__(256)
void k_softmax(float* __restrict__ attn) {
  int blk = blockIdx.x;
  int h = blk >> 11, i = blk & 2047;
  float* p = attn + ((size_t)h << 22) + (size_t)i * 2048;
  int len = i + 1;
  int tid = threadIdx.x;
  float vals[8];
  int nv = 0;
  float m = -1e30f;
  for (int j = tid; j < len; j += 256) {
    float x = p[j];
    vals[nv++] = x;
    m = fmaxf(m, x);
  }
#pragma unroll
  for (int off = 32; off; off >>= 1) m = fmaxf(m, __shfl_down(m, off));
  __shared__ float wred[4];
  if ((tid & 63) == 0) wred[tid >> 6] = m;
  __syncthreads();
  m = fmaxf(fmaxf(wred[0], wred[1]), fmaxf(wred[2], wred[3]));
  float s = 0.f;
  for (int t = 0; t < nv; t++) {
    vals[t] = __expf(vals[t] - m);
    s += vals[t];
  }
#pragma unroll
  for (int off = 32; off; off >>= 1) s += __shfl_down(s, off);
  __shared__ float wsum[4];
  if ((tid & 63) == 0) wsum[tid >> 6] = s;
  __syncthreads();
  s = wsum[0] + wsum[1] + wsum[2] + wsum[3];
  float inv = 1.0f / s;
  nv = 0;
  for (int j = tid; j < len; j += 256) p[j] = vals[nv++] * inv;
}

// ---------------- PV: o[i][h*256+d] = sum_j attn[h][i][j] * v[j][d] ----------------
__global__ __launch_bounds__(256)
void k_pv(const float* __restrict__ attn, const u16* __restrict__ vT,
          u16* __restrict__ o) {
  const int h = blockIdx.z;
  const int i0 = blockIdx.y * 128;
  const int n0 = blockIdx.x * 128;
  const float* Ab = attn + ((size_t)h << 22);
  const int kmax = i0 + 128;
  __shared__ __align__(16) u16 As[128 * 32];
  __shared__ __align__(16) u16 Bs[128 * 32];
  const int tid = threadIdx.x;
  const int wave = tid >> 6, lane = tid & 63;
  const int wm = (wave >> 1) * 64, wn = (wave & 1) * 64;
  const int quad = lane >> 4, r = lane & 15;

  f32x4 acc[4][4] = {};

  const int br = tid >> 2, bc = (tid & 3) * 8;
  const u16* bg0 = vT + (size_t)(n0 + br) * 2048 + bc;
  const u16* bg1 = bg0 + (size_t)64 * 2048;
  const int l0 = tid * 8, l1 = (tid + 256) * 8;
  const int arr = tid >> 3, acc4 = (tid & 7) * 4;
  const float* ag = Ab + (size_t)(i0 + arr) * 2048 + acc4;

  for (int k0 = 0; k0 < kmax; k0 += 32) {
    async_cp16(Bs + l0, bg0); async_cp16(Bs + l1, bg1);
    bg0 += 32; bg1 += 32;
#pragma unroll
    for (int it = 0; it < 4; it++) {
      float4 v = *(const float4*)(ag + (size_t)(it * 32) * 2048 + k0);
      ushort4 w;
      w.x = f2h(v.x); w.y = f2h(v.y); w.z = f2h(v.z); w.w = f2h(v.w);
      *(ushort4*)(As + (arr + it * 32) * 32 + acc4) = w;
    }
    __syncthreads();
    gemm_step(As, Bs, wm, wn, quad, r, acc);
    __syncthreads();
  }
#pragma unroll
  for (int ta = 0; ta < 4; ta++) {
    int row = i0 + wm + ta * 16 + quad * 4;
#pragma unroll
    for (int tb = 0; tb < 4; tb++) {
      int col = h * 256 + n0 + wn + tb * 16 + r;
#pragma unroll
      for (int v = 0; v < 4; v++)
        o[(size_t)(row + v) * 2048 + col] = f2h(acc[ta][tb][v]);
    }
  }
}

extern "C" void kernel_launch(void* const* d_in, const int* in_sizes, int n_in,
                              void* d_out, int out_size, void* d_ws, size_t ws_size,
                              hipStream_t stream) {
  const float* x   = (const float*)d_in[0];
  const int*   pos = (const int*)d_in[1];
  const float* w_q = (const float*)d_in[3];
  const float* w_k = (const float*)d_in[4];
  const float* w_v = (const float*)d_in[5];
  const float* w_o = (const float*)d_in[6];

  float* out  = (float*)d_out;
  float* attn = out + (size_t)2048 * 2048;

  char* ws = (char*)d_ws;
  float* qkv   = (float*)ws;                                   // 2048*2560 fp32
  u16*   xb    = (u16*)(ws + (size_t)2048 * 2560 * 4);         // 2048*2048
  u16*   wqkvT = xb + (size_t)2048 * 2048;                     // 2560*2048
  u16*   woT   = wqkvT + (size_t)2560 * 2048;                  // 2048*2048
  u16*   qh    = woT + (size_t)2048 * 2048;                    // 2048*2048
  u16*   kh    = qh + (size_t)2048 * 2048;                     // 2048*256
  u16*   vT    = kh + (size_t)2048 * 256;                      // 256*2048
  u16*   ob    = vT + (size_t)256 * 2048;                      // 2048*2048

  k_convert_x<<<4096, 256, 0, stream>>>(x, xb);
  k_transpose_all<<<dim3(72, 32), 256, 0, stream>>>(w_q, w_k, w_v, w_o, wqkvT, woT);

  // qkv = x @ [w_q|w_k|w_v]  (M=2048, N=2560, K=2048)
  k_gemm<<<dim3(20, 16), 256, 0, stream>>>(xb, 2048, wqkvT, 2048, qkv, 2560, 2048);

  k_rope<<<(2048 * 1024 + 2048 * 128) / 256, 256, 0, stream>>>(qkv, pos, qh, kh);
  k_transpose<<<dim3(4, 32), 256, 0, stream>>>(qkv + 2304, 2560, vT, 2048, 0);

  k_scores<<<dim3(16, 16, 8), 256, 0, stream>>>(qh, kh, attn);
  k_softmax<<<8 * 2048, 256, 0, stream>>>(attn);
  k_pv<<<dim3(2, 16, 8), 256, 0, stream>>>(attn, vT, ob);

  // out = o @ w_o  (M=2048, N=2048, K=2048)
  k_gemm<<<dim3(16, 16), 256, 0, stream>>>(ob, 2048, woT, 2048, out, 2048, 2048);
}

// Round 3
// 401.699 us; speedup vs baseline: 1.1574x; 1.0830x over previous
//
#include <hip/hip_runtime.h>
#include <hip/hip_bf16.h>
#include <hip/hip_fp16.h>

typedef float f32x4 __attribute__((ext_vector_type(4)));
typedef _Float16 half8 __attribute__((ext_vector_type(8)));
typedef unsigned short u16;

#define DEVI __device__ __forceinline__

DEVI void async_cp16(void* lds, const void* g) {
  __builtin_amdgcn_global_load_lds(
      (const __attribute__((address_space(1))) void*)g,
      (__attribute__((address_space(3))) void*)lds,
      16, 0, 0);
}

DEVI u16 f2h(float x) {
  union { _Float16 h; u16 u; } v;
  v.h = (_Float16)x;
  return v.u;
}

// ---------------- prep: weight transposes + x convert, one launch ----------------
// grid (136, 32): x 0..31 w_q, 32..35 w_k, 36..39 w_v, 40..71 w_o, 72..135 convert x
__global__ __launch_bounds__(256)
void k_prep(const float* __restrict__ x, const float* __restrict__ wq,
            const float* __restrict__ wk, const float* __restrict__ wv,
            const float* __restrict__ wo,
            u16* __restrict__ xb, u16* __restrict__ wqkvT, u16* __restrict__ woT) {
  int bx = blockIdx.x;
  if (bx >= 72) {  // convert x: 64x32 blocks, 2048 elems each
    size_t base = ((size_t)(bx - 72) * 32 + blockIdx.y) * 2048 + threadIdx.x * 8;
    float4 v0 = *(const float4*)(x + base);
    float4 v1 = *(const float4*)(x + base + 4);
    ushort4 o0, o1;
    o0.x = f2h(v0.x); o0.y = f2h(v0.y); o0.z = f2h(v0.z); o0.w = f2h(v0.w);
    o1.x = f2h(v1.x); o1.y = f2h(v1.y); o1.z = f2h(v1.z); o1.w = f2h(v1.w);
    *(ushort4*)(xb + base) = o0;
    *(ushort4*)(xb + base + 4) = o1;
    return;
  }
  __shared__ u16 tile[64][65];
  const float* in; int ldin, rowoff, cx; u16* out;
  if (bx < 32)      { in = wq; ldin = 2048; out = wqkvT; rowoff = 0;    cx = bx; }
  else if (bx < 36) { in = wk; ldin = 256;  out = wqkvT; rowoff = 2048; cx = bx - 32; }
  else if (bx < 40) { in = wv; ldin = 256;  out = wqkvT; rowoff = 2304; cx = bx - 36; }
  else              { in = wo; ldin = 2048; out = woT;   rowoff = 0;    cx = bx - 40; }
  int r0 = blockIdx.y * 64, c0 = cx * 64;
  int tx = threadIdx.x & 63, ty = threadIdx.x >> 6;
  for (int rr = ty; rr < 64; rr += 4)
    tile[rr][tx] = f2h(in[(size_t)(r0 + rr) * ldin + (c0 + tx)]);
  __syncthreads();
  for (int rr = ty; rr < 64; rr += 4)
    out[(size_t)(c0 + rr + rowoff) * 2048 + (r0 + tx)] = tile[tx][rr];
}

// ---------------- generic transpose + convert (used for vT) ----------------
__global__ __launch_bounds__(256) void k_transpose(const float* __restrict__ in, int ldin,
                                                   u16* __restrict__ out, int ldout) {
  __shared__ u16 tile[64][65];
  int r0 = blockIdx.y * 64, c0 = blockIdx.x * 64;
  int tx = threadIdx.x & 63, ty = threadIdx.x >> 6;
  for (int rr = ty; rr < 64; rr += 4)
    tile[rr][tx] = f2h(in[(size_t)(r0 + rr) * ldin + (c0 + tx)]);
  __syncthreads();
  for (int rr = ty; rr < 64; rr += 4)
    out[(size_t)(c0 + rr) * ldout + (r0 + tx)] = tile[tx][rr];
}

// ---------------- dense GEMM: C[M][N]f32 = A[M][K]f16 @ B[N][K]f16^T ----------------
// 64x128 tile, 4 waves of 32x64, BK=32, dbuf. Small tile -> 2-2.5 blocks/CU so
// inter-block TLP hides the barrier's vmcnt(0) drain (m114 mechanism).
__global__ __launch_bounds__(256)
void k_gemm(const u16* __restrict__ A, int lda,
            const u16* __restrict__ B, int ldb,
            float* __restrict__ C, int ldc, int K) {
  __shared__ __align__(16) u16 As[2][64 * 32];
  __shared__ __align__(16) u16 Bs[2][128 * 32];
  const int i0 = blockIdx.y * 64, j0 = blockIdx.x * 128;
  const int tid = threadIdx.x;
  const int wave = tid >> 6, lane = tid & 63;
  const int wm = (wave >> 1) * 32, wn = (wave & 1) * 64;
  const int quad = lane >> 4, r = lane & 15;

  f32x4 acc[2][4] = {};

  const int ar = tid >> 2, ac = (tid & 3) * 8;
  const u16* ag = A + (size_t)(i0 + ar) * lda + ac;
  const u16* bg0 = B + (size_t)(j0 + ar) * ldb + ac;
  const u16* bg1 = bg0 + (size_t)64 * ldb;
  const int l0 = tid * 8, l1 = (tid + 256) * 8;

  async_cp16(As[0] + l0, ag);
  async_cp16(Bs[0] + l0, bg0); async_cp16(Bs[0] + l1, bg1);
  ag += 32; bg0 += 32; bg1 += 32;
  __syncthreads();

  const int nk = K >> 5;  // 64: even
  for (int kt = 0; kt < nk; kt += 2) {
#pragma unroll
    for (int half = 0; half < 2; half++) {
      int cur = half, nxt = half ^ 1;
      if (kt + half + 1 < nk) {
        async_cp16(As[nxt] + l0, ag);
        async_cp16(Bs[nxt] + l0, bg0); async_cp16(Bs[nxt] + l1, bg1);
        ag += 32; bg0 += 32; bg1 += 32;
      }
      half8 af[2], bf[4];
#pragma unroll
      for (int t = 0; t < 2; t++) af[t] = *(const half8*)(As[cur] + (wm + t * 16 + r) * 32 + quad * 8);
#pragma unroll
      for (int t = 0; t < 4; t++) bf[t] = *(const half8*)(Bs[cur] + (wn + t * 16 + r) * 32 + quad * 8);
#pragma unroll
      for (int ta = 0; ta < 2; ta++)
#pragma unroll
        for (int tb = 0; tb < 4; tb++)
          acc[ta][tb] = __builtin_amdgcn_mfma_f32_16x16x32_f16(af[ta], bf[tb], acc[ta][tb], 0, 0, 0);
      __syncthreads();
    }
  }
#pragma unroll
  for (int ta = 0; ta < 2; ta++) {
    int row = i0 + wm + ta * 16 + quad * 4;
#pragma unroll
    for (int tb = 0; tb < 4; tb++) {
      int col = j0 + wn + tb * 16 + r;
      float* cp = C + (size_t)row * ldc + col;
#pragma unroll
      for (int v = 0; v < 4; v++) cp[(size_t)v * ldc] = acc[ta][tb][v];
    }
  }
}

// ---------------- RoPE: qkv fp32 -> q,k fp16 (rotated) ----------------
__global__ __launch_bounds__(256)
void k_rope(const float* __restrict__ qkv, const int* __restrict__ pos,
            u16* __restrict__ qh, u16* __restrict__ kh) {
  int idx = blockIdx.x * 256 + threadIdx.x;
  const int TOTAL_Q = 2048 * 1024;
  int s, i;
  const float* src;
  u16* dst;
  if (idx < TOTAL_Q) {
    s = idx >> 10;
    int hi = idx & 1023;
    int hd = hi >> 7;
    i = hi & 127;
    src = qkv + (size_t)s * 2560 + hd * 256;
    dst = qh + (size_t)s * 2048 + hd * 256;
  } else {
    int t = idx - TOTAL_Q;
    s = t >> 7;
    i = t & 127;
    src = qkv + (size_t)s * 2560 + 2048;
    dst = kh + (size_t)s * 256;
  }
  float p = (float)pos[s];
  float freq = __expf((float)i * (-9.210340371976184f / 128.0f)) * p;
  float sn, cs;
  sincosf(freq, &sn, &cs);
  float a = src[i], b = src[i + 128];
  dst[i]       = f2h(a * cs - b * sn);
  dst[i + 128] = f2h(b * cs + a * sn);
}

// ---------------- scores: attn[h][i][j] = scale * q_h[i]·k[j], causal ----------------
__global__ __launch_bounds__(256)
void k_scores(const u16* __restrict__ qh, const u16* __restrict__ kh,
              float* __restrict__ attn) {
  const int i0 = blockIdx.y * 128, j0 = blockIdx.x * 128;
  const int h = blockIdx.z;
  const int tid = threadIdx.x;
  float* outb = attn + ((size_t)h << 22);
  if (j0 > i0) {  // fully-masked tile: exact zeros
    float4 z = {0.f, 0.f, 0.f, 0.f};
    int row = tid >> 5, col4 = (tid & 31) * 4;
    for (int s = 0; s < 16; s++)
      *(float4*)(outb + (size_t)(i0 + s * 8 + row) * 2048 + j0 + col4) = z;
    return;
  }
  const u16* A = qh + h * 256;
  __shared__ __align__(16) u16 As[2][128 * 32];
  __shared__ __align__(16) u16 Bs[2][128 * 32];
  const int wave = tid >> 6, lane = tid & 63;
  const int wm = (wave >> 1) * 64, wn = (wave & 1) * 64;
  const int quad = lane >> 4, r = lane & 15;

  f32x4 acc[4][4] = {};

  const int ar = tid >> 2, ac = (tid & 3) * 8;
  const u16* ag0 = A + (size_t)(i0 + ar) * 2048 + ac;
  const u16* ag1 = ag0 + (size_t)64 * 2048;
  const u16* bg0 = kh + (size_t)(j0 + ar) * 256 + ac;
  const u16* bg1 = bg0 + (size_t)64 * 256;
  const int l0 = tid * 8, l1 = (tid + 256) * 8;

  async_cp16(As[0] + l0, ag0); async_cp16(As[0] + l1, ag1);
  async_cp16(Bs[0] + l0, bg0); async_cp16(Bs[0] + l1, bg1);
  ag0 += 32; ag1 += 32; bg0 += 32; bg1 += 32;
  __syncthreads();

  for (int kt = 0; kt < 8; kt += 2) {
#pragma unroll
    for (int half = 0; half < 2; half++) {
      int cur = half, nxt = half ^ 1;
      if (kt + half + 1 < 8) {
        async_cp16(As[nxt] + l0, ag0); async_cp16(As[nxt] + l1, ag1);
        async_cp16(Bs[nxt] + l0, bg0); async_cp16(Bs[nxt] + l1, bg1);
        ag0 += 32; ag1 += 32; bg0 += 32; bg1 += 32;
      }
      half8 af[4], bf[4];
#pragma unroll
      for (int t = 0; t < 4; t++) af[t] = *(const half8*)(As[cur] + (wm + t * 16 + r) * 32 + quad * 8);
#pragma unroll
      for (int t = 0; t < 4; t++) bf[t] = *(const half8*)(Bs[cur] + (wn + t * 16 + r) * 32 + quad * 8);
#pragma unroll
      for (int ta = 0; ta < 4; ta++)
#pragma unroll
        for (int tb = 0; tb < 4; tb++)
          acc[ta][tb] = __builtin_amdgcn_mfma_f32_16x16x32_f16(af[ta], bf[tb], acc[ta][tb], 0, 0, 0);
      __syncthreads();
    }
  }
#pragma unroll
  for (int ta = 0; ta < 4; ta++) {
#pragma unroll
    for (int tb = 0; tb < 4; tb++) {
      int col = j0 + wn + tb * 16 + r;
#pragma unroll
      for (int v = 0; v < 4; v++) {
        int row = i0 + wm + ta * 16 + quad * 4 + v;
        outb[(size_t)row * 2048 + col] = (col <= row) ? acc[ta][tb][v] * 0.0625f : 0.0f;
      }
    }
  }
}

// ---------------- row softmax over j<=i, in place, float4 ----------------
__global__ __launch_bounds__(256)
void k_softmax(float* __restrict__ attn) {
  int blk = blockIdx.x;
  int h = blk >> 11, i = blk & 2047;
  float* p = attn + ((size_t)h << 22) + (size_t)i * 2048;
  int len = i + 1;
  int tid = threadIdx.x;
  float4 v0 = *(const float4*)(p + tid * 4);
  float4 v1 = *(const float4*)(p + 1024 + tid * 4);
  float vals[8];
  // predicate padding (j >= len) to -inf so exp -> 0 and sum is clean
#pragma unroll
  for (int c = 0; c < 4; c++) vals[c]     = (tid * 4 + c < len)        ? ((const float*)&v0)[c] : -1e30f;
#pragma unroll
  for (int c = 0; c < 4; c++) vals[4 + c] = (1024 + tid * 4 + c < len) ? ((const float*)&v1)[c] : -1e30f;
  float m = -1e30f;
#pragma unroll
  for (int t = 0; t < 8; t++) m = fmaxf(m, vals[t]);
#pragma unroll
  for (int off = 32; off; off >>= 1) m = fmaxf(m, __shfl_down(m, off));
  __shared__ float wred[4];
  if ((tid & 63) == 0) wred[tid >> 6] = m;
  __syncthreads();
  m = fmaxf(fmaxf(wred[0], wred[1]), fmaxf(wred[2], wred[3]));
  float s = 0.f;
#pragma unroll
  for (int t = 0; t < 8; t++) {
    vals[t] = __expf(vals[t] - m);
    s += vals[t];
  }
#pragma unroll
  for (int off = 32; off; off >>= 1) s += __shfl_down(s, off);
  __shared__ float wsum[4];
  if ((tid & 63) == 0) wsum[tid >> 6] = s;
  __syncthreads();
  s = wsum[0] + wsum[1] + wsum[2] + wsum[3];
  float inv = 1.0f / s;
  float4 o0, o1;
#pragma unroll
  for (int c = 0; c < 4; c++) { ((float*)&o0)[c] = vals[c] * inv; ((float*)&o1)[c] = vals[4 + c] * inv; }
  *(float4*)(p + tid * 4) = o0;
  *(float4*)(p + 1024 + tid * 4) = o1;
}

// ---------------- PV: o[i][h*256+d] = sum_j attn[h][i][j] * v[j][d] ----------------
// 64 rows x 256 cols (full DH) per block -> attn read ONCE. 4 waves of 64x64.
__global__ __launch_bounds__(256)
void k_pv(const float* __restrict__ attn, const u16* __restrict__ vT,
          u16* __restrict__ o) {
  const int h = blockIdx.y;
  const int i0 = blockIdx.x * 64;
  const float* Ab = attn + ((size_t)h << 22);
  const int kmax = i0 + 64;
  __shared__ __align__(16) u16 As[64 * 32];
  __shared__ __align__(16) u16 Bs[256 * 32];
  const int tid = threadIdx.x;
  const int wave = tid >> 6, lane = tid & 63;
  const int wn = wave * 64;
  const int quad = lane >> 4, r = lane & 15;

  f32x4 acc[4][4] = {};

  const int br = tid >> 2, bc = (tid & 3) * 8;
  const u16* bg = vT + (size_t)br * 2048 + bc;
  const int arr = tid >> 2, ac8 = (tid & 3) * 8;
  const float* ag = Ab + (size_t)(i0 + arr) * 2048 + ac8;

  for (int k0 = 0; k0 < kmax; k0 += 32) {
#pragma unroll
    for (int c = 0; c < 4; c++)
      async_cp16(Bs + tid * 8 + c * 2048, bg + (size_t)(c * 64) * 2048 + k0);
    float4 v0 = *(const float4*)(ag + k0);
    float4 v1 = *(const float4*)(ag + k0 + 4);
    ushort4 w0, w1;
    w0.x = f2h(v0.x); w0.y = f2h(v0.y); w0.z = f2h(v0.z); w0.w = f2h(v0.w);
    w1.x = f2h(v1.x); w1.y = f2h(v1.y); w1.z = f2h(v1.z); w1.w = f2h(v1.w);
    *(ushort4*)(As + tid * 8) = w0;
    *(ushort4*)(As + tid * 8 + 4) = w1;
    __syncthreads();
    half8 af[4], bf[4];
#pragma unroll
    for (int t = 0; t < 4; t++) af[t] = *(const half8*)(As + (t * 16 + r) * 32 + quad * 8);
#pragma unroll
    for (int t = 0; t < 4; t++) bf[t] = *(const half8*)(Bs + (wn + t * 16 + r) * 32 + quad * 8);
#pragma unroll
    for (int ta = 0; ta < 4; ta++)
#pragma unroll
      for (int tb = 0; tb < 4; tb++)
        acc[ta][tb] = __builtin_amdgcn_mfma_f32_16x16x32_f16(af[ta], bf[tb], acc[ta][tb], 0, 0, 0);
    __syncthreads();
  }
#pragma unroll
  for (int ta = 0; ta < 4; ta++) {
    int row = i0 + ta * 16 + quad * 4;
#pragma unroll
    for (int tb = 0; tb < 4; tb++) {
      int col = h * 256 + wn + tb * 16 + r;
#pragma unroll
      for (int v = 0; v < 4; v++)
        o[(size_t)(row + v) * 2048 + col] = f2h(acc[ta][tb][v]);
    }
  }
}

extern "C" void kernel_launch(void* const* d_in, const int* in_sizes, int n_in,
                              void* d_out, int out_size, void* d_ws, size_t ws_size,
                              hipStream_t stream) {
  const float* x   = (const float*)d_in[0];
  const int*   pos = (const int*)d_in[1];
  const float* w_q = (const float*)d_in[3];
  const float* w_k = (const float*)d_in[4];
  const float* w_v = (const float*)d_in[5];
  const float* w_o = (const float*)d_in[6];

  float* out  = (float*)d_out;
  float* attn = out + (size_t)2048 * 2048;

  char* ws = (char*)d_ws;
  float* qkv   = (float*)ws;                                   // 2048*2560 fp32
  u16*   xb    = (u16*)(ws + (size_t)2048 * 2560 * 4);         // 2048*2048
  u16*   wqkvT = xb + (size_t)2048 * 2048;                     // 2560*2048
  u16*   woT   = wqkvT + (size_t)2560 * 2048;                  // 2048*2048
  u16*   qh    = woT + (size_t)2048 * 2048;                    // 2048*2048
  u16*   kh    = qh + (size_t)2048 * 2048;                     // 2048*256
  u16*   vT    = kh + (size_t)2048 * 256;                      // 256*2048
  u16*   ob    = vT + (size_t)256 * 2048;                      // 2048*2048

  k_prep<<<dim3(136, 32), 256, 0, stream>>>(x, w_q, w_k, w_v, w_o, xb, wqkvT, woT);

  // qkv = x @ [w_q|w_k|w_v]  (M=2048, N=2560, K=2048), 64x128 tiles -> 640 blocks
  k_gemm<<<dim3(20, 32), 256, 0, stream>>>(xb, 2048, wqkvT, 2048, qkv, 2560, 2048);

  k_rope<<<(2048 * 1024 + 2048 * 128) / 256, 256, 0, stream>>>(qkv, pos, qh, kh);
  k_transpose<<<dim3(4, 32), 256, 0, stream>>>(qkv + 2304, 2560, vT, 2048);

  k_scores<<<dim3(16, 16, 8), 256, 0, stream>>>(qh, kh, attn);
  k_softmax<<<8 * 2048, 256, 0, stream>>>(attn);
  k_pv<<<dim3(32, 8), 256, 0, stream>>>(attn, vT, ob);

  // out = ob @ w_o  (M=2048, N=2048, K=2048), 64x128 tiles -> 512 blocks
  k_gemm<<<dim3(16, 32), 256, 0, stream>>>(ob, 2048, woT, 2048, out, 2048, 2048);
}

// Round 4
// 391.014 us; speedup vs baseline: 1.1890x; 1.0273x over previous
//
#include <hip/hip_runtime.h>
#include <hip/hip_bf16.h>
#include <hip/hip_fp16.h>

typedef float f32x4 __attribute__((ext_vector_type(4)));
typedef _Float16 half8 __attribute__((ext_vector_type(8)));
typedef unsigned short u16;

#define DEVI __device__ __forceinline__

DEVI void async_cp16(void* lds, const void* g) {
  __builtin_amdgcn_global_load_lds(
      (const __attribute__((address_space(1))) void*)g,
      (__attribute__((address_space(3))) void*)lds,
      16, 0, 0);
}

DEVI u16 f2h(float x) {
  union { _Float16 h; u16 u; } v;
  v.h = (_Float16)x;
  return v.u;
}

// ---------------- prep: weight transposes + x convert, one launch ----------------
__global__ __launch_bounds__(256)
void k_prep(const float* __restrict__ x, const float* __restrict__ wq,
            const float* __restrict__ wk, const float* __restrict__ wv,
            const float* __restrict__ wo,
            u16* __restrict__ xb, u16* __restrict__ wqkvT, u16* __restrict__ woT) {
  int bx = blockIdx.x;
  if (bx >= 72) {  // convert x
    size_t base = ((size_t)(bx - 72) * 32 + blockIdx.y) * 2048 + threadIdx.x * 8;
    float4 v0 = *(const float4*)(x + base);
    float4 v1 = *(const float4*)(x + base + 4);
    ushort4 o0, o1;
    o0.x = f2h(v0.x); o0.y = f2h(v0.y); o0.z = f2h(v0.z); o0.w = f2h(v0.w);
    o1.x = f2h(v1.x); o1.y = f2h(v1.y); o1.z = f2h(v1.z); o1.w = f2h(v1.w);
    *(ushort4*)(xb + base) = o0;
    *(ushort4*)(xb + base + 4) = o1;
    return;
  }
  __shared__ u16 tile[64][65];
  const float* in; int ldin, rowoff, cx; u16* out;
  if (bx < 32)      { in = wq; ldin = 2048; out = wqkvT; rowoff = 0;    cx = bx; }
  else if (bx < 36) { in = wk; ldin = 256;  out = wqkvT; rowoff = 2048; cx = bx - 32; }
  else if (bx < 40) { in = wv; ldin = 256;  out = wqkvT; rowoff = 2304; cx = bx - 36; }
  else              { in = wo; ldin = 2048; out = woT;   rowoff = 0;    cx = bx - 40; }
  int r0 = blockIdx.y * 64, c0 = cx * 64;
  int tx = threadIdx.x & 63, ty = threadIdx.x >> 6;
  for (int rr = ty; rr < 64; rr += 4)
    tile[rr][tx] = f2h(in[(size_t)(r0 + rr) * ldin + (c0 + tx)]);
  __syncthreads();
  for (int rr = ty; rr < 64; rr += 4)
    out[(size_t)(c0 + rr + rowoff) * 2048 + (r0 + tx)] = tile[tx][rr];
}

// ---------------- generic transpose + convert (used for vT) ----------------
__global__ __launch_bounds__(256) void k_transpose(const float* __restrict__ in, int ldin,
                                                   u16* __restrict__ out, int ldout) {
  __shared__ u16 tile[64][65];
  int r0 = blockIdx.y * 64, c0 = blockIdx.x * 64;
  int tx = threadIdx.x & 63, ty = threadIdx.x >> 6;
  for (int rr = ty; rr < 64; rr += 4)
    tile[rr][tx] = f2h(in[(size_t)(r0 + rr) * ldin + (c0 + tx)]);
  __syncthreads();
  for (int rr = ty; rr < 64; rr += 4)
    out[(size_t)(c0 + rr) * ldout + (r0 + tx)] = tile[tx][rr];
}

// ---------------- dense GEMM: C[M][N]f32 = A[M][K]f16 @ B[N][K]f16^T ----------------
// 64x128 tile, 4 waves of 32x64, BK=32, dbuf. grid x = M-tile (32 tiles, ≡0 mod 8)
// so blocks sharing an A-stripe land on one XCD (L2 reuse); B costs 8x aggregate.
__global__ __launch_bounds__(256)
void k_gemm(const u16* __restrict__ A, int lda,
            const u16* __restrict__ B, int ldb,
            float* __restrict__ C, int ldc, int K) {
  __shared__ __align__(16) u16 As[2][64 * 32];
  __shared__ __align__(16) u16 Bs[2][128 * 32];
  const int i0 = blockIdx.x * 64, j0 = blockIdx.y * 128;
  const int tid = threadIdx.x;
  const int wave = tid >> 6, lane = tid & 63;
  const int wm = (wave >> 1) * 32, wn = (wave & 1) * 64;
  const int quad = lane >> 4, r = lane & 15;

  f32x4 acc[2][4] = {};

  const int ar = tid >> 2, ac = (tid & 3) * 8;
  const u16* ag = A + (size_t)(i0 + ar) * lda + ac;
  const u16* bg0 = B + (size_t)(j0 + ar) * ldb + ac;
  const u16* bg1 = bg0 + (size_t)64 * ldb;
  const int l0 = tid * 8, l1 = (tid + 256) * 8;

  async_cp16(As[0] + l0, ag);
  async_cp16(Bs[0] + l0, bg0); async_cp16(Bs[0] + l1, bg1);
  ag += 32; bg0 += 32; bg1 += 32;
  __syncthreads();

  const int nk = K >> 5;
  for (int kt = 0; kt < nk; kt += 2) {
#pragma unroll
    for (int half = 0; half < 2; half++) {
      int cur = half, nxt = half ^ 1;
      if (kt + half + 1 < nk) {
        async_cp16(As[nxt] + l0, ag);
        async_cp16(Bs[nxt] + l0, bg0); async_cp16(Bs[nxt] + l1, bg1);
        ag += 32; bg0 += 32; bg1 += 32;
      }
      half8 af[2], bf[4];
#pragma unroll
      for (int t = 0; t < 2; t++) af[t] = *(const half8*)(As[cur] + (wm + t * 16 + r) * 32 + quad * 8);
#pragma unroll
      for (int t = 0; t < 4; t++) bf[t] = *(const half8*)(Bs[cur] + (wn + t * 16 + r) * 32 + quad * 8);
#pragma unroll
      for (int ta = 0; ta < 2; ta++)
#pragma unroll
        for (int tb = 0; tb < 4; tb++)
          acc[ta][tb] = __builtin_amdgcn_mfma_f32_16x16x32_f16(af[ta], bf[tb], acc[ta][tb], 0, 0, 0);
      __syncthreads();
    }
  }
#pragma unroll
  for (int ta = 0; ta < 2; ta++) {
    int row = i0 + wm + ta * 16 + quad * 4;
#pragma unroll
    for (int tb = 0; tb < 4; tb++) {
      int col = j0 + wn + tb * 16 + r;
      float* cp = C + (size_t)row * ldc + col;
#pragma unroll
      for (int v = 0; v < 4; v++) cp[(size_t)v * ldc] = acc[ta][tb][v];
    }
  }
}

// ---------------- RoPE: qkv fp32 -> q,k fp16 (rotated) ----------------
__global__ __launch_bounds__(256)
void k_rope(const float* __restrict__ qkv, const int* __restrict__ pos,
            u16* __restrict__ qh, u16* __restrict__ kh) {
  int idx = blockIdx.x * 256 + threadIdx.x;
  const int TOTAL_Q = 2048 * 1024;
  int s, i;
  const float* src;
  u16* dst;
  if (idx < TOTAL_Q) {
    s = idx >> 10;
    int hi = idx & 1023;
    int hd = hi >> 7;
    i = hi & 127;
    src = qkv + (size_t)s * 2560 + hd * 256;
    dst = qh + (size_t)s * 2048 + hd * 256;
  } else {
    int t = idx - TOTAL_Q;
    s = t >> 7;
    i = t & 127;
    src = qkv + (size_t)s * 2560 + 2048;
    dst = kh + (size_t)s * 256;
  }
  float p = (float)pos[s];
  float freq = __expf((float)i * (-9.210340371976184f / 128.0f)) * p;
  float sn, cs;
  sincosf(freq, &sn, &cs);
  float a = src[i], b = src[i + 128];
  dst[i]       = f2h(a * cs - b * sn);
  dst[i + 128] = f2h(b * cs + a * sn);
}

// ---------------- scores: attn[h][i][j] = exp(scale * q_h[i]·k[j]), causal ----------------
// Writes UNNORMALIZED exp (masked region exactly 0). |s| bounded (<~16) so fp32 exp safe.
__global__ __launch_bounds__(256)
void k_scores(const u16* __restrict__ qh, const u16* __restrict__ kh,
              float* __restrict__ attn) {
  const int i0 = blockIdx.y * 128, j0 = blockIdx.x * 128;
  const int h = blockIdx.z;
  const int tid = threadIdx.x;
  float* outb = attn + ((size_t)h << 22);
  if (j0 > i0) {  // fully-masked tile: exact zeros
    float4 z = {0.f, 0.f, 0.f, 0.f};
    int row = tid >> 5, col4 = (tid & 31) * 4;
    for (int s = 0; s < 16; s++)
      *(float4*)(outb + (size_t)(i0 + s * 8 + row) * 2048 + j0 + col4) = z;
    return;
  }
  const u16* A = qh + h * 256;
  __shared__ __align__(16) u16 As[2][128 * 32];
  __shared__ __align__(16) u16 Bs[2][128 * 32];
  const int wave = tid >> 6, lane = tid & 63;
  const int wm = (wave >> 1) * 64, wn = (wave & 1) * 64;
  const int quad = lane >> 4, r = lane & 15;

  f32x4 acc[4][4] = {};

  const int ar = tid >> 2, ac = (tid & 3) * 8;
  const u16* ag0 = A + (size_t)(i0 + ar) * 2048 + ac;
  const u16* ag1 = ag0 + (size_t)64 * 2048;
  const u16* bg0 = kh + (size_t)(j0 + ar) * 256 + ac;
  const u16* bg1 = bg0 + (size_t)64 * 256;
  const int l0 = tid * 8, l1 = (tid + 256) * 8;

  async_cp16(As[0] + l0, ag0); async_cp16(As[0] + l1, ag1);
  async_cp16(Bs[0] + l0, bg0); async_cp16(Bs[0] + l1, bg1);
  ag0 += 32; ag1 += 32; bg0 += 32; bg1 += 32;
  __syncthreads();

  for (int kt = 0; kt < 8; kt += 2) {
#pragma unroll
    for (int half = 0; half < 2; half++) {
      int cur = half, nxt = half ^ 1;
      if (kt + half + 1 < 8) {
        async_cp16(As[nxt] + l0, ag0); async_cp16(As[nxt] + l1, ag1);
        async_cp16(Bs[nxt] + l0, bg0); async_cp16(Bs[nxt] + l1, bg1);
        ag0 += 32; ag1 += 32; bg0 += 32; bg1 += 32;
      }
      half8 af[4], bf[4];
#pragma unroll
      for (int t = 0; t < 4; t++) af[t] = *(const half8*)(As[cur] + (wm + t * 16 + r) * 32 + quad * 8);
#pragma unroll
      for (int t = 0; t < 4; t++) bf[t] = *(const half8*)(Bs[cur] + (wn + t * 16 + r) * 32 + quad * 8);
#pragma unroll
      for (int ta = 0; ta < 4; ta++)
#pragma unroll
        for (int tb = 0; tb < 4; tb++)
          acc[ta][tb] = __builtin_amdgcn_mfma_f32_16x16x32_f16(af[ta], bf[tb], acc[ta][tb], 0, 0, 0);
      __syncthreads();
    }
  }
#pragma unroll
  for (int ta = 0; ta < 4; ta++) {
#pragma unroll
    for (int tb = 0; tb < 4; tb++) {
      int col = j0 + wn + tb * 16 + r;
#pragma unroll
      for (int v = 0; v < 4; v++) {
        int row = i0 + wm + ta * 16 + quad * 4 + v;
        outb[(size_t)row * 2048 + col] =
            (col <= row) ? __expf(acc[ta][tb][v] * 0.0625f) : 0.0f;
      }
    }
  }
}

// ---------------- fused softmax-normalize + PV ----------------
// Block owns 32 exclusive attn rows x full DH (256 cols). Pass 1: row sums of exp.
// Pass 2 (K-loop): read exp (L2-hot), normalize, write attn back in place, stage
// fp16, MFMA with vT. o[i][h*256+d] = sum_j p[i][j] v[j][d].
__global__ __launch_bounds__(256)
void k_pv(float* __restrict__ attn, const u16* __restrict__ vT,
          u16* __restrict__ o) {
  const int h = blockIdx.y;
  const int i0 = blockIdx.x * 32;
  float* Ab = attn + ((size_t)h << 22);
  const int kmax = i0 + 32;
  __shared__ __align__(16) u16 As[32 * 32];
  __shared__ __align__(16) u16 Bs[256 * 32];
  __shared__ float inv_l[32];
  const int tid = threadIdx.x;
  const int wave = tid >> 6, lane = tid & 63;
  const int wn = wave * 64;
  const int quad = lane >> 4, r = lane & 15;

  // ---- pass 1: row sums over live cols 0..kmax-1 ----
  {
    int row = tid >> 3, sub = tid & 7;
    const float* rp = Ab + (size_t)(i0 + row) * 2048;
    float s = 0.f;
    for (int c = sub * 4; c < kmax; c += 32) {
      float4 v = *(const float4*)(rp + c);
      s += v.x + v.y + v.z + v.w;
    }
    s += __shfl_xor(s, 1); s += __shfl_xor(s, 2); s += __shfl_xor(s, 4);
    if (sub == 0) inv_l[row] = 1.0f / s;
  }
  __syncthreads();

  f32x4 acc[2][4] = {};
  const int br = tid >> 2, bc = (tid & 3) * 8;
  const u16* bg = vT + (size_t)br * 2048 + bc;
  const int arr = tid >> 3, ac4 = (tid & 7) * 4;
  float* agp = Ab + (size_t)(i0 + arr) * 2048 + ac4;
  const float ainv = inv_l[arr];

  for (int k0 = 0; k0 < kmax; k0 += 32) {
#pragma unroll
    for (int c = 0; c < 4; c++)
      async_cp16(Bs + tid * 8 + c * 2048, bg + (size_t)(c * 64) * 2048 + k0);
    float4 v = *(const float4*)(agp + k0);
    v.x *= ainv; v.y *= ainv; v.z *= ainv; v.w *= ainv;
    *(float4*)(agp + k0) = v;            // normalized attn written in place
    ushort4 w;
    w.x = f2h(v.x); w.y = f2h(v.y); w.z = f2h(v.z); w.w = f2h(v.w);
    *(ushort4*)(As + arr * 32 + ac4) = w;
    __syncthreads();
    half8 af[2], bf[4];
#pragma unroll
    for (int t = 0; t < 2; t++) af[t] = *(const half8*)(As + (t * 16 + r) * 32 + quad * 8);
#pragma unroll
    for (int t = 0; t < 4; t++) bf[t] = *(const half8*)(Bs + (wn + t * 16 + r) * 32 + quad * 8);
#pragma unroll
    for (int ta = 0; ta < 2; ta++)
#pragma unroll
      for (int tb = 0; tb < 4; tb++)
        acc[ta][tb] = __builtin_amdgcn_mfma_f32_16x16x32_f16(af[ta], bf[tb], acc[ta][tb], 0, 0, 0);
    __syncthreads();
  }
#pragma unroll
  for (int ta = 0; ta < 2; ta++) {
    int row = i0 + ta * 16 + quad * 4;
#pragma unroll
    for (int tb = 0; tb < 4; tb++) {
      int col = h * 256 + wn + tb * 16 + r;
#pragma unroll
      for (int v = 0; v < 4; v++)
        o[(size_t)(row + v) * 2048 + col] = f2h(acc[ta][tb][v]);
    }
  }
}

extern "C" void kernel_launch(void* const* d_in, const int* in_sizes, int n_in,
                              void* d_out, int out_size, void* d_ws, size_t ws_size,
                              hipStream_t stream) {
  const float* x   = (const float*)d_in[0];
  const int*   pos = (const int*)d_in[1];
  const float* w_q = (const float*)d_in[3];
  const float* w_k = (const float*)d_in[4];
  const float* w_v = (const float*)d_in[5];
  const float* w_o = (const float*)d_in[6];

  float* out  = (float*)d_out;
  float* attn = out + (size_t)2048 * 2048;

  char* ws = (char*)d_ws;
  float* qkv   = (float*)ws;                                   // 2048*2560 fp32
  u16*   xb    = (u16*)(ws + (size_t)2048 * 2560 * 4);         // 2048*2048
  u16*   wqkvT = xb + (size_t)2048 * 2048;                     // 2560*2048
  u16*   woT   = wqkvT + (size_t)2560 * 2048;                  // 2048*2048
  u16*   qh    = woT + (size_t)2048 * 2048;                    // 2048*2048
  u16*   kh    = qh + (size_t)2048 * 2048;                     // 2048*256
  u16*   vT    = kh + (size_t)2048 * 256;                      // 256*2048
  u16*   ob    = vT + (size_t)256 * 2048;                      // 2048*2048

  k_prep<<<dim3(136, 32), 256, 0, stream>>>(x, w_q, w_k, w_v, w_o, xb, wqkvT, woT);

  // qkv = x @ [w_q|w_k|w_v]  (M=2048, N=2560, K=2048); grid x = M-tiles
  k_gemm<<<dim3(32, 20), 256, 0, stream>>>(xb, 2048, wqkvT, 2048, qkv, 2560, 2048);

  k_rope<<<(2048 * 1024 + 2048 * 128) / 256, 256, 0, stream>>>(qkv, pos, qh, kh);
  k_transpose<<<dim3(4, 32), 256, 0, stream>>>(qkv + 2304, 2560, vT, 2048);

  k_scores<<<dim3(16, 16, 8), 256, 0, stream>>>(qh, kh, attn);
  k_pv<<<dim3(64, 8), 256, 0, stream>>>(attn, vT, ob);

  // out = ob @ w_o  (M=2048, N=2048, K=2048); grid x = M-tiles
  k_gemm<<<dim3(32, 16), 256, 0, stream>>>(ob, 2048, woT, 2048, out, 2048, 2048);
}